// Round 1
// baseline (357.034 us; speedup 1.0000x reference)
//
#include <hip/hip_runtime.h>

// Masked BCE: cost = sum(t==1 ? -log(p) : t==0 ? -log(1-p) : 0) / count(t<=1)
// Memory-bound streaming reduction: 2 × 163.84 MB read, scalar out.

__global__ __launch_bounds__(256) void bce_reduce_kernel(
    const float* __restrict__ prob,
    const int* __restrict__ tgt,
    float* __restrict__ ws_sum,
    unsigned int* __restrict__ ws_cnt,
    long long n4, long long n)
{
    const long long tid    = (long long)blockIdx.x * blockDim.x + threadIdx.x;
    const long long stride = (long long)gridDim.x * blockDim.x;

    float        lsum = 0.0f;
    unsigned int lcnt = 0u;

    const float4* __restrict__ p4 = (const float4*)prob;
    const int4*   __restrict__ t4 = (const int4*)tgt;

    for (long long i = tid; i < n4; i += stride) {
        float4 p = p4[i];
        int4   t = t4[i];

        {
            float v = (t.x == 1) ? p.x : 1.0f - p.x;
            float l = -logf(v);
            bool  c = (unsigned)t.x <= 1u;
            lsum += c ? l : 0.0f;
            lcnt += c ? 1u : 0u;
        }
        {
            float v = (t.y == 1) ? p.y : 1.0f - p.y;
            float l = -logf(v);
            bool  c = (unsigned)t.y <= 1u;
            lsum += c ? l : 0.0f;
            lcnt += c ? 1u : 0u;
        }
        {
            float v = (t.z == 1) ? p.z : 1.0f - p.z;
            float l = -logf(v);
            bool  c = (unsigned)t.z <= 1u;
            lsum += c ? l : 0.0f;
            lcnt += c ? 1u : 0u;
        }
        {
            float v = (t.w == 1) ? p.w : 1.0f - p.w;
            float l = -logf(v);
            bool  c = (unsigned)t.w <= 1u;
            lsum += c ? l : 0.0f;
            lcnt += c ? 1u : 0u;
        }
    }

    // scalar tail (n not divisible by 4)
    for (long long i = n4 * 4 + tid; i < n; i += stride) {
        float p = prob[i];
        int   t = tgt[i];
        float v = (t == 1) ? p : 1.0f - p;
        float l = -logf(v);
        bool  c = (unsigned)t <= 1u;
        lsum += c ? l : 0.0f;
        lcnt += c ? 1u : 0u;
    }

    // wave-64 reduction
    #pragma unroll
    for (int off = 32; off > 0; off >>= 1) {
        lsum += __shfl_down(lsum, off, 64);
        lcnt += __shfl_down(lcnt, off, 64);
    }

    // cross-wave reduction via LDS (256 threads -> 4 waves)
    __shared__ float        s_sum[4];
    __shared__ unsigned int s_cnt[4];
    const int lane = threadIdx.x & 63;
    const int wave = threadIdx.x >> 6;
    if (lane == 0) {
        s_sum[wave] = lsum;
        s_cnt[wave] = lcnt;
    }
    __syncthreads();
    if (threadIdx.x == 0) {
        float        bsum = s_sum[0] + s_sum[1] + s_sum[2] + s_sum[3];
        unsigned int bcnt = s_cnt[0] + s_cnt[1] + s_cnt[2] + s_cnt[3];
        atomicAdd(ws_sum, bsum);
        atomicAdd(ws_cnt, bcnt);
    }
}

__global__ void bce_finalize_kernel(const float* __restrict__ ws_sum,
                                    const unsigned int* __restrict__ ws_cnt,
                                    float* __restrict__ out)
{
    out[0] = ws_sum[0] / (float)ws_cnt[0];
}

extern "C" void kernel_launch(void* const* d_in, const int* in_sizes, int n_in,
                              void* d_out, int out_size, void* d_ws, size_t ws_size,
                              hipStream_t stream) {
    const float* prob = (const float*)d_in[0];
    const int*   tgt  = (const int*)d_in[1];
    float*       out  = (float*)d_out;

    const long long n  = (long long)in_sizes[0];
    const long long n4 = n / 4;

    float*        ws_sum = (float*)d_ws;
    unsigned int* ws_cnt = (unsigned int*)((char*)d_ws + sizeof(float));

    // zero the accumulators (ws is poisoned 0xAA before every launch)
    hipMemsetAsync(d_ws, 0, sizeof(float) + sizeof(unsigned int), stream);

    const int block = 256;
    const int grid  = 2048;  // 8 blocks/CU on 256 CUs, grid-stride covers the rest

    bce_reduce_kernel<<<grid, block, 0, stream>>>(prob, tgt, ws_sum, ws_cnt, n4, n);
    bce_finalize_kernel<<<1, 1, 0, stream>>>(ws_sum, ws_cnt, out);
}

// Round 2
// 329.698 us; speedup vs baseline: 1.0829x; 1.0829x over previous
//
#include <hip/hip_runtime.h>

// Masked BCE: cost = sum(t==1 ? -log(p) : t==0 ? -log(1-p) : 0) / count(t<=1)
// Streaming reduction, 328 MB read. No same-address atomics: per-block
// partials in d_ws, finalize kernel reduces them.

#define GRID_BLOCKS 2048
#define BLOCK 256

__global__ __launch_bounds__(BLOCK) void bce_reduce_kernel(
    const float* __restrict__ prob,
    const int* __restrict__ tgt,
    float* __restrict__ part_sum,        // [GRID_BLOCKS]
    unsigned int* __restrict__ part_cnt, // [GRID_BLOCKS]
    int n)                               // total elements (fits int32)
{
    const int tid    = blockIdx.x * BLOCK + threadIdx.x;
    const int stride = GRID_BLOCKS * BLOCK;

    const int n4  = n >> 2;        // float4 count
    const int n4h = n4 >> 1;       // half-range for 2-way MLP

    float        lsum = 0.0f;
    unsigned int lcnt = 0u;

    const float4* __restrict__ p4 = (const float4*)prob;
    const int4*   __restrict__ t4 = (const int4*)tgt;

    // main loop: two independent float4+int4 streams -> 4 loads in flight
    for (int i = tid; i < n4h; i += stride) {
        float4 pa = p4[i];
        int4   ta = t4[i];
        float4 pb = p4[i + n4h];
        int4   tb = t4[i + n4h];

        #define ACC(P, T)                                   \
        {                                                   \
            float v = ((T) == 1) ? (P) : 1.0f - (P);        \
            bool  c = (unsigned)(T) <= 1u;                  \
            float l = -__logf(v);                           \
            lsum += c ? l : 0.0f;                           \
            lcnt += c ? 1u : 0u;                            \
        }
        ACC(pa.x, ta.x) ACC(pa.y, ta.y) ACC(pa.z, ta.z) ACC(pa.w, ta.w)
        ACC(pb.x, tb.x) ACC(pb.y, tb.y) ACC(pb.z, tb.z) ACC(pb.w, tb.w)
    }

    // tail: elements [2*n4h*4, n)
    for (int i = (n4h * 2) * 4 + tid; i < n; i += stride) {
        float p = prob[i];
        int   t = tgt[i];
        float v = (t == 1) ? p : 1.0f - p;
        bool  c = (unsigned)t <= 1u;
        float l = -__logf(v);
        lsum += c ? l : 0.0f;
        lcnt += c ? 1u : 0u;
    }

    // wave-64 reduction
    #pragma unroll
    for (int off = 32; off > 0; off >>= 1) {
        lsum += __shfl_down(lsum, off, 64);
        lcnt += __shfl_down(lcnt, off, 64);
    }

    // cross-wave via LDS (4 waves)
    __shared__ float        s_sum[4];
    __shared__ unsigned int s_cnt[4];
    const int lane = threadIdx.x & 63;
    const int wave = threadIdx.x >> 6;
    if (lane == 0) { s_sum[wave] = lsum; s_cnt[wave] = lcnt; }
    __syncthreads();
    if (threadIdx.x == 0) {
        part_sum[blockIdx.x] = s_sum[0] + s_sum[1] + s_sum[2] + s_sum[3];
        part_cnt[blockIdx.x] = s_cnt[0] + s_cnt[1] + s_cnt[2] + s_cnt[3];
    }
}

__global__ __launch_bounds__(BLOCK) void bce_finalize_kernel(
    const float* __restrict__ part_sum,
    const unsigned int* __restrict__ part_cnt,
    float* __restrict__ out)
{
    float        lsum = 0.0f;
    unsigned int lcnt = 0u;
    for (int i = threadIdx.x; i < GRID_BLOCKS; i += BLOCK) {
        lsum += part_sum[i];
        lcnt += part_cnt[i];
    }
    #pragma unroll
    for (int off = 32; off > 0; off >>= 1) {
        lsum += __shfl_down(lsum, off, 64);
        lcnt += __shfl_down(lcnt, off, 64);
    }
    __shared__ float        s_sum[4];
    __shared__ unsigned int s_cnt[4];
    const int lane = threadIdx.x & 63;
    const int wave = threadIdx.x >> 6;
    if (lane == 0) { s_sum[wave] = lsum; s_cnt[wave] = lcnt; }
    __syncthreads();
    if (threadIdx.x == 0) {
        float        bsum = s_sum[0] + s_sum[1] + s_sum[2] + s_sum[3];
        unsigned int bcnt = s_cnt[0] + s_cnt[1] + s_cnt[2] + s_cnt[3];
        out[0] = bsum / (float)bcnt;
    }
}

extern "C" void kernel_launch(void* const* d_in, const int* in_sizes, int n_in,
                              void* d_out, int out_size, void* d_ws, size_t ws_size,
                              hipStream_t stream) {
    const float* prob = (const float*)d_in[0];
    const int*   tgt  = (const int*)d_in[1];
    float*       out  = (float*)d_out;

    const int n = in_sizes[0];

    float*        part_sum = (float*)d_ws;
    unsigned int* part_cnt = (unsigned int*)((char*)d_ws + GRID_BLOCKS * sizeof(float));

    bce_reduce_kernel<<<GRID_BLOCKS, BLOCK, 0, stream>>>(prob, tgt, part_sum, part_cnt, n);
    bce_finalize_kernel<<<1, BLOCK, 0, stream>>>(part_sum, part_cnt, out);
}